// Round 8
// baseline (108.146 us; speedup 1.0000x reference)
//
#include <hip/hip_runtime.h>
#include <hip/hip_bf16.h>

// PrototypicalNetwork: out[q,c] = -1/8 * sum_b sqrt(max(q2[q] + p2[b,c] - 2*qp[b,q,c], 0))
// bf16 MFMA 16x16x32 for qp GEMM (M=65536, N=1024, K=128).
// R14 = R13 (measured best 107.8us) with COMPUTE_B restructured for
// MFMA||VALU pipe overlap (T15 mechanism): both jj MFMA clusters issue
// back-to-back (32 MFMAs in one setprio span), THEN the jj=0 sqrt epilogue
// runs on the VALU while jj=1's MFMAs still execute in the matrix pipe.
// Previously each jj's epilogue serialized against its own MFMA cluster.
// Cost: second live qp set (+16 regs, ~230 of the 256 unified budget at
// 2 waves/EU -- R13 post-mortem established the budget is unified, not
// 128 arch). Zero new memory traffic.

#define DIM   128
#define NCLS  128
#define SHOTS 32
#define NB    8
#define NQ    65536

using short8 = __attribute__((ext_vector_type(8))) short;
using f32x4  = __attribute__((ext_vector_type(4))) float;

__device__ __forceinline__ unsigned short f2bf(float x) {
  union { float f; unsigned u; } v; v.f = x;
  unsigned r = v.u + 0x7fffu + ((v.u >> 16) & 1u);   // RNE
  return (unsigned short)(r >> 16);
}

__device__ __forceinline__ short8 pack8_bf16(float4 a, float4 b) {
  // v_cvt_pk_bf16_f32 on gfx950 (RNE), 4 insts for 8 elements
  __hip_bfloat162 p0 = __float22bfloat162_rn(make_float2(a.x, a.y));
  __hip_bfloat162 p1 = __float22bfloat162_rn(make_float2(a.z, a.w));
  __hip_bfloat162 p2 = __float22bfloat162_rn(make_float2(b.x, b.y));
  __hip_bfloat162 p3 = __float22bfloat162_rn(make_float2(b.z, b.w));
  union { __hip_bfloat162 h[4]; short8 s; } u;
  u.h[0] = p0; u.h[1] = p1; u.h[2] = p2; u.h[3] = p3;
  return u.s;
}

__device__ __forceinline__ float fast_sqrt(float x) {
#if __has_builtin(__builtin_amdgcn_sqrtf)
  return __builtin_amdgcn_sqrtf(x);   // raw v_sqrt_f32 (never IEEE sqrtf here — R3 regression)
#else
  return sqrtf(x);
#endif
}

// ---------------------------------------------------------------------------
// Kernel 1: bootstrap-mean protos -> bf16(-proto/32) in MFMA B-frag-major
// layout, plus p2[b,c] = |proto|^2 / 64 (fp32).
// B-frag layout (16x16x32): lane holds B[n=lane&15][k=(lane>>4)*8+j].
// Slot = (b*8+ct)*4+kiter; one slot = 64 lanes * 16 B = 1 KB contiguous.
// ---------------------------------------------------------------------------
__global__ __launch_bounds__(128) void proto_kernel(
    const float* __restrict__ sup, const int* __restrict__ bidx,
    unsigned short* __restrict__ pfrag, float* __restrict__ p2) {
  int bc = blockIdx.x;            // b*128 + c
  int c  = bc & (NCLS - 1);
  int d  = threadIdx.x;           // 0..127 = feature dim
  __shared__ int   sidx[SHOTS];
  __shared__ float wsum[2];
  if (d < SHOTS) sidx[d] = bidx[bc * SHOTS + d];
  __syncthreads();
  float acc = 0.f;
  const float* base = sup + c * SHOTS * DIM + d;
  #pragma unroll
  for (int s = 0; s < SHOTS; ++s) acc += base[sidx[s] * DIM];
  float proto = acc * (1.0f / 32.0f);

  int b     = bc >> 7;
  int ct    = c >> 4, l15c = c & 15;
  int kiter = d >> 5, quad = (d >> 3) & 3, j = d & 7;
  int lane  = l15c + (quad << 4);
  int slot  = (b * 8 + ct) * 4 + kiter;
  pfrag[slot * 512 + lane * 8 + j] = f2bf(proto * -0.03125f);  // -proto/32

  float sq = proto * proto;
  #pragma unroll
  for (int off = 32; off > 0; off >>= 1) sq += __shfl_down(sq, off, 64);
  if ((d & 63) == 0) wsum[d >> 6] = sq;
  __syncthreads();
  if (d == 0) p2[bc] = (wsum[0] + wsum[1]) * (1.0f / 64.0f);
}

// ---------------------------------------------------------------------------
// Kernel 2: block = 64 query rows x 128 classes, 4 waves, grid 1024.
// Stage: wave w converts rows [16w, 16w+16) to A-frag layout in LDS (two
// passes of the 8-row pattern). Then each wave reads all 16 A-frags
// (4mt x 4k) and runs the ping-pong b-loop over its 2 c-tiles: each 8-KB
// B-frag load feeds 4 m-tiles. One barrier total.
// ---------------------------------------------------------------------------
#define SLOT_STRIDE 520   // 512 shorts payload + 8 pad -> slot base moves 4 banks

__global__ __launch_bounds__(256, 2) void dist_kernel(
    const float* __restrict__ q, const uint4* __restrict__ pfrag,
    const float* __restrict__ p2, float* __restrict__ out) {
  int tid  = threadIdx.x;
  int w    = tid >> 6, lane = tid & 63;
  int l15  = lane & 15, quad = lane >> 4;
  int q0   = blockIdx.x << 6;                        // 64 rows per block

  __shared__ unsigned short aflds[16 * SLOT_STRIDE]; // A-frags, slot = mt*4 + i
  __shared__ float q2s[64];                          // |q|^2 per row (unscaled)

  // --- staging: this wave converts rows 16w..16w+15; lane = (row_local, chunk)
  // chunk = 16-float slice of D. A-frag target: slot (mt, i=chunk>>1), within
  // slot position p = quad*16 + m, 8 shorts each; this lane covers quads
  // (chunk&1)*2 and (chunk&1)*2+1 of row m.
  #pragma unroll
  for (int pass = 0; pass < 2; ++pass) {
    int rloc  = w * 16 + pass * 8 + (lane >> 3);     // 0..63 local row
    int chunk = lane & 7;
    const float* src = q + (size_t)(q0 + rloc) * DIM + chunk * 16;
    float4 x0 = *reinterpret_cast<const float4*>(src);
    float4 x1 = *reinterpret_cast<const float4*>(src + 4);
    float4 x2 = *reinterpret_cast<const float4*>(src + 8);
    float4 x3 = *reinterpret_cast<const float4*>(src + 12);
    float s = x0.x*x0.x + x0.y*x0.y + x0.z*x0.z + x0.w*x0.w
            + x1.x*x1.x + x1.y*x1.y + x1.z*x1.z + x1.w*x1.w
            + x2.x*x2.x + x2.y*x2.y + x2.z*x2.z + x2.w*x2.w
            + x3.x*x3.x + x3.y*x3.y + x3.z*x3.z + x3.w*x3.w;
    s += __shfl_down(s, 4, 8);              // reduce over the row's 8 chunks
    s += __shfl_down(s, 2, 8);
    s += __shfl_down(s, 1, 8);
    if (chunk == 0) q2s[rloc] = s;

    int mt = rloc >> 4, m = rloc & 15, i = chunk >> 1, h = chunk & 1;
    unsigned short* base = &aflds[(mt * 4 + i) * SLOT_STRIDE];
    *reinterpret_cast<short8*>(&base[((h * 2 + 0) * 16 + m) * 8]) = pack8_bf16(x0, x1);
    *reinterpret_cast<short8*>(&base[((h * 2 + 1) * 16 + m) * 8]) = pack8_bf16(x2, x3);
  }
  __syncthreads();

  // --- every wave pulls all 16 A-frags + q2' from LDS ---
  short8 af[4][4];
  #pragma unroll
  for (int mt = 0; mt < 4; ++mt)
    #pragma unroll
    for (int k = 0; k < 4; ++k)
      af[mt][k] = *reinterpret_cast<const short8*>(
          &aflds[(mt * 4 + k) * SLOT_STRIDE + lane * 8]);

  f32x4 q2r[4];                    // q2' for C/D row quad*4+r of each m-tile
  #pragma unroll
  for (int mt = 0; mt < 4; ++mt)
    #pragma unroll
    for (int r = 0; r < 4; ++r)
      q2r[mt][r] = q2s[mt * 16 + quad * 4 + r] * (1.0f / 64.0f);

  f32x4 oacc[4][2];
  #pragma unroll
  for (int mt = 0; mt < 4; ++mt)
    #pragma unroll
    for (int jj = 0; jj < 2; ++jj)
      oacc[mt][jj] = (f32x4){0.f, 0.f, 0.f, 0.f};

  // --- b-loop: X/Y ping-pong, 8 frag loads + 2 p2 scalars in flight ---
  uint4 bufX[8], bufY[8];
  float ppX0, ppX1, ppY0, ppY1;    // p2' scalars, named (no runtime indexing)

  #define LOAD_B(BUF, P0, P1, B)                                              \
    {                                                                         \
      _Pragma("unroll")                                                       \
      for (int jj = 0; jj < 2; ++jj) {                                        \
        int ct = w * 2 + jj;                                                  \
        const uint4* bp = pfrag + (size_t)(((B) * 8 + ct) * 4) * 64 + lane;   \
        _Pragma("unroll")                                                     \
        for (int k = 0; k < 4; ++k) BUF[jj * 4 + k] = bp[k * 64];             \
      }                                                                       \
      P0 = p2[(B) * NCLS + (w * 2 + 0) * 16 + l15];                           \
      P1 = p2[(B) * NCLS + (w * 2 + 1) * 16 + l15];                           \
    }

  // Both jj MFMA clusters issue back-to-back; epilogue of jj=0 overlaps the
  // matrix-pipe execution of jj=1's cluster (separate pipes, in-order issue).
  #define COMPUTE_B(BUF, P0, P1)                                              \
    {                                                                         \
      f32x4 qp0[4], qp1[4];                                                   \
      _Pragma("unroll")                                                       \
      for (int mt = 0; mt < 4; ++mt)                                          \
        _Pragma("unroll")                                                     \
        for (int r = 0; r < 4; ++r) {                                         \
          qp0[mt][r] = q2r[mt][r] + P0;                                       \
          qp1[mt][r] = q2r[mt][r] + P1;                                       \
        }                                                                     \
      __builtin_amdgcn_s_setprio(1);                                          \
      _Pragma("unroll")                                                       \
      for (int k = 0; k < 4; ++k) {                                           \
        short8 bf0 = __builtin_bit_cast(short8, BUF[k]);                      \
        _Pragma("unroll")                                                     \
        for (int mt = 0; mt < 4; ++mt)                                        \
          qp0[mt] = __builtin_amdgcn_mfma_f32_16x16x32_bf16(af[mt][k], bf0, qp0[mt], 0, 0, 0); \
      }                                                                       \
      _Pragma("unroll")                                                       \
      for (int k = 0; k < 4; ++k) {                                           \
        short8 bf1 = __builtin_bit_cast(short8, BUF[4 + k]);                  \
        _Pragma("unroll")                                                     \
        for (int mt = 0; mt < 4; ++mt)                                        \
          qp1[mt] = __builtin_amdgcn_mfma_f32_16x16x32_bf16(af[mt][k], bf1, qp1[mt], 0, 0, 0); \
      }                                                                       \
      __builtin_amdgcn_s_setprio(0);                                          \
      _Pragma("unroll")                                                       \
      for (int mt = 0; mt < 4; ++mt)                                          \
        _Pragma("unroll")                                                     \
        for (int r = 0; r < 4; ++r)                                           \
          oacc[mt][0][r] += fast_sqrt(fmaxf(qp0[mt][r], 0.0f));               \
      _Pragma("unroll")                                                       \
      for (int mt = 0; mt < 4; ++mt)                                          \
        _Pragma("unroll")                                                     \
        for (int r = 0; r < 4; ++r)                                           \
          oacc[mt][1][r] += fast_sqrt(fmaxf(qp1[mt][r], 0.0f));               \
    }

  LOAD_B(bufX, ppX0, ppX1, 0)
  #pragma unroll 1
  for (int i = 0; i < NB; i += 2) {
    LOAD_B(bufY, ppY0, ppY1, i + 1)               // in flight across X's compute
    COMPUTE_B(bufX, ppX0, ppX1)
    LOAD_B(bufX, ppX0, ppX1, (i + 2) & (NB - 1))  // wraps to b=0 on last iter
    COMPUTE_B(bufY, ppY0, ppY1)
  }
  #undef LOAD_B
  #undef COMPUTE_B

  // --- store: row = q0 + mt2*16 + quad*4 + r, col = (2w+jj)*16 + l15 ---
  #pragma unroll
  for (int mt2 = 0; mt2 < 4; ++mt2)
    #pragma unroll
    for (int jj = 0; jj < 2; ++jj) {
      int col = (w * 2 + jj) * 16 + l15;
      #pragma unroll
      for (int r = 0; r < 4; ++r) {
        int row = q0 + mt2 * 16 + quad * 4 + r;
        out[(size_t)row * NCLS + col] = -oacc[mt2][jj][r];
      }
    }
}

extern "C" void kernel_launch(void* const* d_in, const int* in_sizes, int n_in,
                              void* d_out, int out_size, void* d_ws, size_t ws_size,
                              hipStream_t stream) {
  const float* sup   = (const float*)d_in[0];   // [4096,128] f32
  // d_in[1] = support_labels (unused: sorted/balanced by construction)
  const float* query = (const float*)d_in[2];   // [65536,128] f32
  const int*   bidx  = (const int*)d_in[3];     // [8,128,32] i32
  float* out = (float*)d_out;                   // [65536,128] f32

  unsigned short* pfrag = (unsigned short*)d_ws;              // 256 KB bf16 frags
  float* p2 = (float*)((char*)d_ws + (size_t)NB * NCLS * DIM * 2); // 4 KB

  proto_kernel<<<NB * NCLS, 128, 0, stream>>>(sup, bidx, pfrag, p2);
  dist_kernel<<<NQ / 64, 256, 0, stream>>>(query, (const uint4*)pfrag, p2, out);
}